// Round 5
// baseline (212.828 us; speedup 1.0000x reference)
//
#include <hip/hip_runtime.h>

typedef __bf16 bf16;
typedef __bf16 bf16x4v __attribute__((ext_vector_type(4)));
typedef __bf16 bf16x8 __attribute__((ext_vector_type(8)));
typedef float f32x4 __attribute__((ext_vector_type(4)));
typedef short s16x4 __attribute__((ext_vector_type(4)));

#define MFMA_X32(A, B, C) __builtin_amdgcn_mfma_f32_16x16x32_bf16(A, B, C, 0, 0, 0)

#if __has_builtin(__builtin_amdgcn_mfma_f32_16x16x16_bf16)
static __device__ __forceinline__ f32x4 mfma_x16(bf16x4v a, bf16x4v b, f32x4 c) {
  return __builtin_amdgcn_mfma_f32_16x16x16_bf16(a, b, c, 0, 0, 0);
}
#else
static __device__ __forceinline__ f32x4 mfma_x16(bf16x4v a, bf16x4v b, f32x4 c) {
  return __builtin_amdgcn_mfma_f32_16x16x16bf16_1k(
      __builtin_bit_cast(s16x4, a), __builtin_bit_cast(s16x4, b), c, 0, 0, 0);
}
#endif

static __device__ __forceinline__ float fast_exp2(float x) {
  float r;
  asm volatile("v_exp_f32 %0, %1\n\ts_nop 0" : "=v"(r) : "v"(x));
  return r;
}

static __device__ __forceinline__ void gll16(const void* g, void* l) {
  __builtin_amdgcn_global_load_lds(
      (const __attribute__((address_space(1))) void*)g,
      (__attribute__((address_space(3))) void*)l, 16, 0, 0);
}

// ---- workspace byte offsets ----
#define WT_OFF 0              // Wt bf16 [3][256 n][256 k]          (384 KB)
#define Q_OFF 393216          // Q' bf16 [16384][256] (pre-scaled)   (8 MB)
#define K_OFF 8781824         // Kc bf16 chunk-permuted              (8 MB)
#define V_OFF 17170432        // Vc bf16 chunk-permuted              (8 MB)
// Kc: per (b, 16-key chunk) 8KB block; element (key s, dim n) at
//   (n>>5)*512 + ((n>>3)&3)*128 + (s&15)*8 + (n&7)
//   => flash K-frag ds_read_b128 addr = base + kt*1024 + lane*16 (LINEAR).
// Vc: per (b, 16-key chunk) 8KB block; element (key s, dim d=n) at
//   (n>>4)*256 + ((s&15)>>2)*64 + (n&15)*4 + (s&3)
//   => flash V-frag ds_read_b64 addr = base + dt*512 + lane*8 (LINEAR).
// (R3 layouts — R4's dt-paired variant reverted with the rest of R4.)

// ---------------------------------------------------------------------------
// Kernel 1: W [k][n] fp32 -> Wt bf16 [p][n][k]
// ---------------------------------------------------------------------------
__global__ __launch_bounds__(256) void prep_wt(const float* __restrict__ Wq,
                                               const float* __restrict__ Wk,
                                               const float* __restrict__ Wv,
                                               bf16* __restrict__ Wt) {
  const int idx = blockIdx.x * 256 + threadIdx.x;
  const int p = idx >> 16;
  const int rem = idx & 65535;  // k*256 + n
  const int k = rem >> 8, n = rem & 255;
  const float* W = (p == 0) ? Wq : ((p == 1) ? Wk : Wv);
  Wt[p * 65536 + n * 256 + k] = (bf16)W[rem];
}

// ---------------------------------------------------------------------------
// Kernel 2: QKV projection v3 — barrier-free main loop. 256 blocks x 64-row
// tiles; x staged once in LDS (33 KB; ONE __syncthreads in the whole kernel);
// p-loop inside so x HBM traffic is 16.7 MB total. Wt B-fragments are read
// DIRECTLY from global (L2-hot 128 KB/p; no LDS staging, none of R3's 24
// barriers). Q pre-scaled by log2e/sqrt(D); K/V written in the flash LDS
// permutations.
// ---------------------------------------------------------------------------
__global__ __launch_bounds__(256, 3) void proj_qkv(const float* __restrict__ x,
                                                   const float* __restrict__ bq,
                                                   const float* __restrict__ bk,
                                                   const float* __restrict__ bv,
                                                   char* __restrict__ ws0) {
  __shared__ __align__(16) bf16 xs[64][264];  // 33 KB
  const bf16* Wt = (const bf16*)(ws0 + WT_OFF);
  bf16* Qo = (bf16*)(ws0 + Q_OFF);
  bf16* Ko = (bf16*)(ws0 + K_OFF);
  bf16* Vc = (bf16*)(ws0 + V_OFF);
  const int t = threadIdx.x;
  const int rowbase = blockIdx.x * 64;

  {  // stage x tile (64x256 fp32 -> bf16), coalesced float4
    const int rr = t >> 6, c4 = (t & 63) * 4;
#pragma unroll 4
    for (int i = 0; i < 16; ++i) {
      const int r = i * 4 + rr;
      const float4 v = *(const float4*)&x[(rowbase + r) * 256 + c4];
      bf16x4v h;
      h[0] = (bf16)v.x; h[1] = (bf16)v.y; h[2] = (bf16)v.z; h[3] = (bf16)v.w;
      *(bf16x4v*)&xs[r][c4] = h;
    }
  }
  __syncthreads();  // the only barrier in this kernel
  const int lane = t & 63, w = t >> 6, l16 = lane & 15, quad = lane >> 4;

  bf16x8 a[8];  // persistent A-frags: wave's 16 rows, K=256
#pragma unroll
  for (int kt = 0; kt < 8; ++kt)
    a[kt] = *(const bf16x8*)&xs[w * 16 + l16][kt * 32 + quad * 8];

  for (int p = 0; p < 3; ++p) {
    const bf16* Wp = Wt + p * 65536;
    f32x4 acc[16];
#pragma unroll
    for (int nt = 0; nt < 16; ++nt) acc[nt] = f32x4{0.f, 0.f, 0.f, 0.f};
#pragma unroll
    for (int kt = 0; kt < 8; ++kt)
#pragma unroll
      for (int nt = 0; nt < 16; ++nt) {  // 16 independent chains; B straight
        const bf16x8 bfr =            // from L2 (global_load_dwordx4)
            *(const bf16x8*)&Wp[(nt * 16 + l16) * 256 + kt * 32 + quad * 8];
        acc[nt] = MFMA_X32(a[kt], bfr, acc[nt]);
      }

    const float* bias = (p == 0) ? bq : ((p == 1) ? bk : bv);
    const float sc = (p == 0) ? 0.09016844005556021f : 1.0f;  // log2e/16
#pragma unroll
    for (int nt = 0; nt < 16; ++nt) {
      const int n = nt * 16 + l16;
      const float bb = bias[n];
#pragma unroll
      for (int r = 0; r < 4; ++r) {
        const int row = rowbase + w * 16 + quad * 4 + r;  // C/D: row=quad*4+r
        const bf16 hv = (bf16)((acc[nt][r] + bb) * sc);
        if (p == 0) {
          Qo[row * 256 + n] = hv;
        } else {
          const int b2 = row >> 11, s = row & 2047;
          if (p == 1)
            Ko[b2 * 524288 + (s >> 4) * 4096 + (n >> 5) * 512 +
               ((n >> 3) & 3) * 128 + (s & 15) * 8 + (n & 7)] = hv;
          else
            Vc[b2 * 524288 + (s >> 4) * 4096 + (n >> 4) * 256 +
               (((s & 15) >> 2)) * 64 + (n & 15) * 4 + (s & 3)] = hv;
        }
      }
    }
  }
}

// ---------------------------------------------------------------------------
// Kernel 3: flash attention — byte-identical to R3 (known-correct, 95 µs,
// 0 bank conflicts). 8 waves = (qs, kq); wave = 32 Q rows x 512 keys.
// 16-key double-buffered chunks via global_load_lds; all LDS fragment reads
// are base+lane*16 / base+lane*8 LINEAR (conflict-free by construction).
// Sᵀ = K·Q'ᵀ (16x16x32) -> C-frags feed PV (16x16x16) with no transpose.
// ---------------------------------------------------------------------------
#define BUF_SZ 65536   // half: 4 kq * (K 8KB + V 8KB), no pads
#define SLOT_SZ 16640  // merge slot: 16 rows * 260 floats

__global__ __launch_bounds__(512, 2) void flash_attn(const char* __restrict__ ws0,
                                                     float* __restrict__ out) {
  __shared__ __align__(1024) char smem[135168];  // 2*BUF_SZ + merge scratch
  const bf16* Qp = (const bf16*)(ws0 + Q_OFF);
  const int t = threadIdx.x;
  const int lane = t & 63, w = t >> 6;
  const int l16 = lane & 15, quad = lane >> 4;
  const int qs = w & 1, kq = w >> 1;
  const int b = blockIdx.x & 7;  // batch == XCD round-robin: K/V L2-resident
  const int qt = blockIdx.x >> 3;
  const int qrow0 = b * 2048 + qt * 64 + qs * 32;

  bf16x8 qf[2][8];
#pragma unroll
  for (int qsub = 0; qsub < 2; ++qsub)
#pragma unroll
    for (int kt = 0; kt < 8; ++kt)
      qf[qsub][kt] =
          *(const bf16x8*)&Qp[(qrow0 + qsub * 16 + l16) * 256 + kt * 32 + quad * 8];

  f32x4 o[2][16];
#pragma unroll
  for (int qsub = 0; qsub < 2; ++qsub)
#pragma unroll
    for (int dt = 0; dt < 16; ++dt) o[qsub][dt] = f32x4{0.f, 0.f, 0.f, 0.f};
  float m_[2] = {-1e30f, -1e30f}, l_[2] = {0.f, 0.f};

  // staging assignment: 8 GLL units (1 KB each) per wave per iter
  unsigned goff[8], loff[8];
#pragma unroll
  for (int i = 0; i < 8; ++i) {
    const int u = w * 8 + i;
    const int kq2 = (u & 31) >> 3, e = u & 7;
    goff[i] = (u < 32 ? (unsigned)K_OFF : (unsigned)V_OFF) + b * 1048576u +
              kq2 * 262144u + e * 1024u + lane * 16u;
    loff[i] = kq2 * 16384u + (u < 32 ? 0u : 8192u) + e * 1024u;
  }
#pragma unroll
  for (int i = 0; i < 8; ++i) gll16(ws0 + goff[i], smem + loff[i]);

  for (int it = 0; it < 32; ++it) {
    __syncthreads();  // chunk `it` resident; prev-iter reads of `nxt` done
    const unsigned cur = (unsigned)(it & 1) * BUF_SZ;
    if (it + 1 < 32) {
      const unsigned nxt = (unsigned)((it + 1) & 1) * BUF_SZ;
      const unsigned gadd = (unsigned)(it + 1) * 8192u;
#pragma unroll
      for (int i = 0; i < 8; ++i) gll16(ws0 + goff[i] + gadd, smem + nxt + loff[i]);
    }

    // ---- Sᵀ = K_chunk · Q'ᵀ (16 keys x 32 q); K reads LINEAR b128 ----
    const char* kb = smem + cur + kq * 16384 + lane * 16;
    f32x4 s0 = f32x4{0.f, 0.f, 0.f, 0.f}, s1 = s0;
#pragma unroll
    for (int kt = 0; kt < 8; ++kt) {
      const bf16x8 kf = *(const bf16x8*)(kb + kt * 1024);
      s0 = MFMA_X32(kf, qf[0][kt], s0);
      s1 = MFMA_X32(kf, qf[1][kt], s1);
    }

    // ---- online softmax (log2 domain; q = l16, key = quad*4+r) ----
    bf16x4v pa[2];
#pragma unroll
    for (int qsub = 0; qsub < 2; ++qsub) {
      const f32x4 s = qsub ? s1 : s0;
      float cm = fmaxf(fmaxf(s[0], s[1]), fmaxf(s[2], s[3]));
      cm = fmaxf(cm, __shfl_xor(cm, 16));
      cm = fmaxf(cm, __shfl_xor(cm, 32));
      const float mold = m_[qsub];
      const float mnew = fmaxf(mold, cm);
      bf16x4v pp;
      float ps = 0.f;
#pragma unroll
      for (int r = 0; r < 4; ++r) {
        const float e = fast_exp2(s[r] - mnew);
        const bf16 pb = (bf16)e;
        pp[r] = pb;
        ps += (float)pb;  // sum ROUNDED p for O/l consistency
      }
      ps += __shfl_xor(ps, 16);
      ps += __shfl_xor(ps, 32);
      if (__any(mnew > mold)) {
        const float al = fast_exp2(mold - mnew);
        m_[qsub] = mnew;
        l_[qsub] = l_[qsub] * al + ps;
        float ar[4];
#pragma unroll
        for (int r = 0; r < 4; ++r)
          ar[r] = __shfl(al, (quad << 4) + (quad << 2) + r);
#pragma unroll
        for (int dt = 0; dt < 16; ++dt)
#pragma unroll
          for (int r = 0; r < 4; ++r) o[qsub][dt][r] *= ar[r];
      } else {
        l_[qsub] += ps;
      }
      pa[qsub] = pp;  // Sᵀ C-frag == PV A-frag
    }

    // ---- O += P · V; V reads LINEAR b64 ----
    const char* vb = smem + cur + kq * 16384 + 8192 + lane * 8;
#pragma unroll
    for (int dt = 0; dt < 16; ++dt) {
      const bf16x4v vf = *(const bf16x4v*)(vb + dt * 512);
      o[0][dt] = mfma_x16(pa[0], vf, o[0][dt]);
      o[1][dt] = mfma_x16(pa[1], vf, o[1][dt]);
    }
  }

  // ---- merge 4 kq partials ----
  float* mlf = (float*)(smem + 133120);  // beyond both buffers: no race
  if (quad == 0) {
#pragma unroll
    for (int qsub = 0; qsub < 2; ++qsub) {
      const int base = ((kq * 2 + qs) * 2 + qsub) * 32;
      mlf[base + l16] = m_[qsub];
      mlf[base + 16 + l16] = l_[qsub];
    }
  }
  __syncthreads();
#pragma unroll
  for (int qsub = 0; qsub < 2; ++qsub) {
    float M = -1e30f, mk[4], lk[4];
#pragma unroll
    for (int k2 = 0; k2 < 4; ++k2) {
      const int base = ((k2 * 2 + qs) * 2 + qsub) * 32;
      mk[k2] = mlf[base + l16];
      lk[k2] = mlf[base + 16 + l16];
      M = fmaxf(M, mk[k2]);
    }
    float L = 0.f;
#pragma unroll
    for (int k2 = 0; k2 < 4; ++k2) L += lk[k2] * fast_exp2(mk[k2] - M);
    const float sg = fast_exp2(m_[qsub] - M) / L;
    float sr[4];
#pragma unroll
    for (int r = 0; r < 4; ++r) sr[r] = __shfl(sg, (quad << 4) + (quad << 2) + r);
#pragma unroll
    for (int dt = 0; dt < 16; ++dt)
#pragma unroll
      for (int r = 0; r < 4; ++r) o[qsub][dt][r] *= sr[r];
  }
  if (kq >= 2) {
#pragma unroll
    for (int qsub = 0; qsub < 2; ++qsub) {
      float* sb = (float*)(smem + ((kq - 2) * 4 + qs * 2 + qsub) * SLOT_SZ);
#pragma unroll
      for (int dt = 0; dt < 16; ++dt)
#pragma unroll
        for (int r = 0; r < 4; ++r)
          sb[(quad * 4 + r) * 260 + dt * 16 + l16] = o[qsub][dt][r];
    }
  }
  __syncthreads();
  if (kq < 2) {
#pragma unroll
    for (int qsub = 0; qsub < 2; ++qsub) {
      const float* sb = (const float*)(smem + (kq * 4 + qs * 2 + qsub) * SLOT_SZ);
#pragma unroll
      for (int dt = 0; dt < 16; ++dt)
#pragma unroll
        for (int r = 0; r < 4; ++r)
          o[qsub][dt][r] += sb[(quad * 4 + r) * 260 + dt * 16 + l16];
    }
  }
  __syncthreads();
  if (kq == 1) {
#pragma unroll
    for (int qsub = 0; qsub < 2; ++qsub) {
      float* sb = (float*)(smem + (qs * 2 + qsub) * SLOT_SZ);
#pragma unroll
      for (int dt = 0; dt < 16; ++dt)
#pragma unroll
        for (int r = 0; r < 4; ++r)
          sb[(quad * 4 + r) * 260 + dt * 16 + l16] = o[qsub][dt][r];
    }
  }
  __syncthreads();
  if (kq == 0) {
#pragma unroll
    for (int qsub = 0; qsub < 2; ++qsub) {
      const float* sb = (const float*)(smem + (qs * 2 + qsub) * SLOT_SZ);
#pragma unroll
      for (int dt = 0; dt < 16; ++dt)
#pragma unroll
        for (int r = 0; r < 4; ++r) {
          const float v = o[qsub][dt][r] + sb[(quad * 4 + r) * 260 + dt * 16 + l16];
          out[(qrow0 + qsub * 16 + quad * 4 + r) * 256 + dt * 16 + l16] = v;
        }
    }
  }
}

extern "C" void kernel_launch(void* const* d_in, const int* in_sizes, int n_in,
                              void* d_out, int out_size, void* d_ws,
                              size_t ws_size, hipStream_t stream) {
  const float* x = (const float*)d_in[0];
  const float* Wq = (const float*)d_in[1];
  const float* bq = (const float*)d_in[2];
  const float* Wk = (const float*)d_in[3];
  const float* bk = (const float*)d_in[4];
  const float* Wv = (const float*)d_in[5];
  const float* bv = (const float*)d_in[6];
  float* out = (float*)d_out;
  char* ws = (char*)d_ws;

  prep_wt<<<768, 256, 0, stream>>>(Wq, Wk, Wv, (bf16*)(ws + WT_OFF));
  proj_qkv<<<256, 256, 0, stream>>>(x, bq, bk, bv, ws);
  flash_attn<<<256, 512, 0, stream>>>(ws, out);
}

// Round 7
// 205.363 us; speedup vs baseline: 1.0363x; 1.0363x over previous
//
#include <hip/hip_runtime.h>

typedef __bf16 bf16;
typedef __bf16 bf16x4v __attribute__((ext_vector_type(4)));
typedef __bf16 bf16x8 __attribute__((ext_vector_type(8)));
typedef float f32x4 __attribute__((ext_vector_type(4)));
typedef short s16x4 __attribute__((ext_vector_type(4)));

#define MFMA_X32(A, B, C) __builtin_amdgcn_mfma_f32_16x16x32_bf16(A, B, C, 0, 0, 0)

#if __has_builtin(__builtin_amdgcn_mfma_f32_16x16x16_bf16)
static __device__ __forceinline__ f32x4 mfma_x16(bf16x4v a, bf16x4v b, f32x4 c) {
  return __builtin_amdgcn_mfma_f32_16x16x16_bf16(a, b, c, 0, 0, 0);
}
#else
static __device__ __forceinline__ f32x4 mfma_x16(bf16x4v a, bf16x4v b, f32x4 c) {
  return __builtin_amdgcn_mfma_f32_16x16x16bf16_1k(
      __builtin_bit_cast(s16x4, a), __builtin_bit_cast(s16x4, b), c, 0, 0, 0);
}
#endif

static __device__ __forceinline__ float fast_exp2(float x) {
  float r;
  asm volatile("v_exp_f32 %0, %1\n\ts_nop 0" : "=v"(r) : "v"(x));
  return r;
}

static __device__ __forceinline__ void gll16(const void* g, void* l) {
  __builtin_amdgcn_global_load_lds(
      (const __attribute__((address_space(1))) void*)g,
      (__attribute__((address_space(3))) void*)l, 16, 0, 0);
}

// ---- workspace byte offsets ----
#define WT_OFF 0              // Wt bf16 [3][256 n][256 k]          (384 KB)
#define Q_OFF 393216          // Q' bf16 [16384][256] (pre-scaled)   (8 MB)
#define K_OFF 8781824         // Kc bf16 chunk-permuted              (8 MB)
#define V_OFF 17170432        // Vc bf16 chunk-permuted              (8 MB)
// Kc: per (b, 16-key chunk) 8KB block; element (key s, dim n) at
//   (n>>5)*512 + ((n>>3)&3)*128 + (s&15)*8 + (n&7)
//   => flash K-frag ds_read_b128 addr = base + kt*1024 + lane*16 (LINEAR).
// Vc: per (b, 16-key chunk) 8KB block; element (key s, dim d=n) at
//   (n>>4)*256 + ((s&15)>>2)*64 + (n&15)*4 + (s&3)
//   => flash V-frag ds_read_b64 addr = base + dt*512 + lane*8 (LINEAR).
// (R3-verified layouts, unchanged.)

// ---------------------------------------------------------------------------
// Kernel 1: W [k][n] fp32 -> Wt bf16 [p][n][k]
// ---------------------------------------------------------------------------
__global__ __launch_bounds__(256) void prep_wt(const float* __restrict__ Wq,
                                               const float* __restrict__ Wk,
                                               const float* __restrict__ Wv,
                                               bf16* __restrict__ Wt) {
  const int idx = blockIdx.x * 256 + threadIdx.x;
  const int p = idx >> 16;
  const int rem = idx & 65535;  // k*256 + n
  const int k = rem >> 8, n = rem & 255;
  const float* W = (p == 0) ? Wq : ((p == 1) ? Wk : Wv);
  Wt[p * 65536 + n * 256 + k] = (bf16)W[rem];
}

// ---------------------------------------------------------------------------
// Kernel 2: QKV projection v4 — occupancy-first, ZERO LDS / ZERO barriers.
// (single change this round vs the R5-verified pipeline)
// 1024 blocks x 16-row tiles x 4 waves (wave = 16 rows x 64 cols) = 4
// blocks/CU = 4 waves/SIMD. A-frags converted straight from global fp32; Wt
// B-frags straight from L2 (393 MB aggregate / 34.5 TB/s ~= 12 µs floor).
// ---------------------------------------------------------------------------
__global__ __launch_bounds__(256, 4) void proj_qkv(const float* __restrict__ x,
                                                   const float* __restrict__ bq,
                                                   const float* __restrict__ bk,
                                                   const float* __restrict__ bv,
                                                   char* __restrict__ ws0) {
  const bf16* Wt = (const bf16*)(ws0 + WT_OFF);
  bf16* Qo = (bf16*)(ws0 + Q_OFF);
  bf16* Ko = (bf16*)(ws0 + K_OFF);
  bf16* Vc = (bf16*)(ws0 + V_OFF);
  const int t = threadIdx.x;
  const int lane = t & 63, w = t >> 6, l16 = lane & 15, quad = lane >> 4;
  const int rowbase = blockIdx.x * 16;

  bf16x8 a[8];  // A-frags: row = l16, k = kt*32 + quad*8 .. +8
#pragma unroll
  for (int kt = 0; kt < 8; ++kt) {
    const float* xp = &x[(rowbase + l16) * 256 + kt * 32 + quad * 8];
    const float4 v0 = *(const float4*)xp;
    const float4 v1 = *(const float4*)(xp + 4);
    bf16x8 h;
    h[0] = (bf16)v0.x; h[1] = (bf16)v0.y; h[2] = (bf16)v0.z; h[3] = (bf16)v0.w;
    h[4] = (bf16)v1.x; h[5] = (bf16)v1.y; h[6] = (bf16)v1.z; h[7] = (bf16)v1.w;
    a[kt] = h;
  }

  for (int p = 0; p < 3; ++p) {
    const bf16* Wp = Wt + p * 65536;
    f32x4 acc[4];
#pragma unroll
    for (int nt = 0; nt < 4; ++nt) acc[nt] = f32x4{0.f, 0.f, 0.f, 0.f};
#pragma unroll
    for (int kt = 0; kt < 8; ++kt)
#pragma unroll
      for (int nt = 0; nt < 4; ++nt) {  // 4 independent chains, B from L2
        const bf16x8 bfr = *(const bf16x8*)&Wp[(w * 64 + nt * 16 + l16) * 256 +
                                               kt * 32 + quad * 8];
        acc[nt] = MFMA_X32(a[kt], bfr, acc[nt]);
      }

    const float* bias = (p == 0) ? bq : ((p == 1) ? bk : bv);
    const float sc = (p == 0) ? 0.09016844005556021f : 1.0f;  // log2e/16
#pragma unroll
    for (int nt = 0; nt < 4; ++nt) {
      const int n = w * 64 + nt * 16 + l16;
      const float bb = bias[n];
#pragma unroll
      for (int r = 0; r < 4; ++r) {
        const int row = rowbase + quad * 4 + r;  // C/D: row = quad*4 + r
        const bf16 hv = (bf16)((acc[nt][r] + bb) * sc);
        if (p == 0) {
          Qo[row * 256 + n] = hv;
        } else {
          const int b2 = row >> 11, s = row & 2047;
          if (p == 1)
            Ko[b2 * 524288 + (s >> 4) * 4096 + (n >> 5) * 512 +
               ((n >> 3) & 3) * 128 + (s & 15) * 8 + (n & 7)] = hv;
          else
            Vc[b2 * 524288 + (s >> 4) * 4096 + (n >> 4) * 256 +
               (((s & 15) >> 2)) * 64 + (n & 15) * 4 + (s & 3)] = hv;
        }
      }
    }
  }
}

// ---------------------------------------------------------------------------
// Kernel 3: flash attention — byte-identical to R5's PASSING kernel
// (online-max softmax; static-max is falsified twice and abandoned).
// ---------------------------------------------------------------------------
#define BUF_SZ 65536   // half: 4 kq * (K 8KB + V 8KB), no pads
#define SLOT_SZ 16640  // merge slot: 16 rows * 260 floats

__global__ __launch_bounds__(512, 2) void flash_attn(const char* __restrict__ ws0,
                                                     float* __restrict__ out) {
  __shared__ __align__(1024) char smem[135168];  // 2*BUF_SZ + merge scratch
  const bf16* Qp = (const bf16*)(ws0 + Q_OFF);
  const int t = threadIdx.x;
  const int lane = t & 63, w = t >> 6;
  const int l16 = lane & 15, quad = lane >> 4;
  const int qs = w & 1, kq = w >> 1;
  const int b = blockIdx.x & 7;  // batch == XCD round-robin: K/V L2-resident
  const int qt = blockIdx.x >> 3;
  const int qrow0 = b * 2048 + qt * 64 + qs * 32;

  bf16x8 qf[2][8];
#pragma unroll
  for (int qsub = 0; qsub < 2; ++qsub)
#pragma unroll
    for (int kt = 0; kt < 8; ++kt)
      qf[qsub][kt] =
          *(const bf16x8*)&Qp[(qrow0 + qsub * 16 + l16) * 256 + kt * 32 + quad * 8];

  f32x4 o[2][16];
#pragma unroll
  for (int qsub = 0; qsub < 2; ++qsub)
#pragma unroll
    for (int dt = 0; dt < 16; ++dt) o[qsub][dt] = f32x4{0.f, 0.f, 0.f, 0.f};
  float m_[2] = {-1e30f, -1e30f}, l_[2] = {0.f, 0.f};

  // staging assignment: 8 GLL units (1 KB each) per wave per iter
  unsigned goff[8], loff[8];
#pragma unroll
  for (int i = 0; i < 8; ++i) {
    const int u = w * 8 + i;
    const int kq2 = (u & 31) >> 3, e = u & 7;
    goff[i] = (u < 32 ? (unsigned)K_OFF : (unsigned)V_OFF) + b * 1048576u +
              kq2 * 262144u + e * 1024u + lane * 16u;
    loff[i] = kq2 * 16384u + (u < 32 ? 0u : 8192u) + e * 1024u;
  }
#pragma unroll
  for (int i = 0; i < 8; ++i) gll16(ws0 + goff[i], smem + loff[i]);

  for (int it = 0; it < 32; ++it) {
    __syncthreads();  // chunk `it` resident; prev-iter reads of `nxt` done
    const unsigned cur = (unsigned)(it & 1) * BUF_SZ;
    if (it + 1 < 32) {
      const unsigned nxt = (unsigned)((it + 1) & 1) * BUF_SZ;
      const unsigned gadd = (unsigned)(it + 1) * 8192u;
#pragma unroll
      for (int i = 0; i < 8; ++i) gll16(ws0 + goff[i] + gadd, smem + nxt + loff[i]);
    }

    // ---- Sᵀ = K_chunk · Q'ᵀ (16 keys x 32 q); K reads LINEAR b128 ----
    const char* kb = smem + cur + kq * 16384 + lane * 16;
    f32x4 s0 = f32x4{0.f, 0.f, 0.f, 0.f}, s1 = s0;
#pragma unroll
    for (int kt = 0; kt < 8; ++kt) {
      const bf16x8 kf = *(const bf16x8*)(kb + kt * 1024);
      s0 = MFMA_X32(kf, qf[0][kt], s0);
      s1 = MFMA_X32(kf, qf[1][kt], s1);
    }

    // ---- online softmax (log2 domain; q = l16, key = quad*4+r) ----
    bf16x4v pa[2];
#pragma unroll
    for (int qsub = 0; qsub < 2; ++qsub) {
      const f32x4 s = qsub ? s1 : s0;
      float cm = fmaxf(fmaxf(s[0], s[1]), fmaxf(s[2], s[3]));
      cm = fmaxf(cm, __shfl_xor(cm, 16));
      cm = fmaxf(cm, __shfl_xor(cm, 32));
      const float mold = m_[qsub];
      const float mnew = fmaxf(mold, cm);
      bf16x4v pp;
      float ps = 0.f;
#pragma unroll
      for (int r = 0; r < 4; ++r) {
        const float e = fast_exp2(s[r] - mnew);
        const bf16 pb = (bf16)e;
        pp[r] = pb;
        ps += (float)pb;  // sum ROUNDED p for O/l consistency
      }
      ps += __shfl_xor(ps, 16);
      ps += __shfl_xor(ps, 32);
      if (__any(mnew > mold)) {
        const float al = fast_exp2(mold - mnew);
        m_[qsub] = mnew;
        l_[qsub] = l_[qsub] * al + ps;
        float ar[4];
#pragma unroll
        for (int r = 0; r < 4; ++r)
          ar[r] = __shfl(al, (quad << 4) + (quad << 2) + r);
#pragma unroll
        for (int dt = 0; dt < 16; ++dt)
#pragma unroll
          for (int r = 0; r < 4; ++r) o[qsub][dt][r] *= ar[r];
      } else {
        l_[qsub] += ps;
      }
      pa[qsub] = pp;  // Sᵀ C-frag == PV A-frag
    }

    // ---- O += P · V; V reads LINEAR b64 ----
    const char* vb = smem + cur + kq * 16384 + 8192 + lane * 8;
#pragma unroll
    for (int dt = 0; dt < 16; ++dt) {
      const bf16x4v vf = *(const bf16x4v*)(vb + dt * 512);
      o[0][dt] = mfma_x16(pa[0], vf, o[0][dt]);
      o[1][dt] = mfma_x16(pa[1], vf, o[1][dt]);
    }
  }

  // ---- merge 4 kq partials ----
  float* mlf = (float*)(smem + 133120);  // beyond both buffers: no race
  if (quad == 0) {
#pragma unroll
    for (int qsub = 0; qsub < 2; ++qsub) {
      const int base = ((kq * 2 + qs) * 2 + qsub) * 32;
      mlf[base + l16] = m_[qsub];
      mlf[base + 16 + l16] = l_[qsub];
    }
  }
  __syncthreads();
#pragma unroll
  for (int qsub = 0; qsub < 2; ++qsub) {
    float M = -1e30f, mk[4], lk[4];
#pragma unroll
    for (int k2 = 0; k2 < 4; ++k2) {
      const int base = ((k2 * 2 + qs) * 2 + qsub) * 32;
      mk[k2] = mlf[base + l16];
      lk[k2] = mlf[base + 16 + l16];
      M = fmaxf(M, mk[k2]);
    }
    float L = 0.f;
#pragma unroll
    for (int k2 = 0; k2 < 4; ++k2) L += lk[k2] * fast_exp2(mk[k2] - M);
    const float sg = fast_exp2(m_[qsub] - M) / L;
    float sr[4];
#pragma unroll
    for (int r = 0; r < 4; ++r) sr[r] = __shfl(sg, (quad << 4) + (quad << 2) + r);
#pragma unroll
    for (int dt = 0; dt < 16; ++dt)
#pragma unroll
      for (int r = 0; r < 4; ++r) o[qsub][dt][r] *= sr[r];
  }
  if (kq >= 2) {
#pragma unroll
    for (int qsub = 0; qsub < 2; ++qsub) {
      float* sb = (float*)(smem + ((kq - 2) * 4 + qs * 2 + qsub) * SLOT_SZ);
#pragma unroll
      for (int dt = 0; dt < 16; ++dt)
#pragma unroll
        for (int r = 0; r < 4; ++r)
          sb[(quad * 4 + r) * 260 + dt * 16 + l16] = o[qsub][dt][r];
    }
  }
  __syncthreads();
  if (kq < 2) {
#pragma unroll
    for (int qsub = 0; qsub < 2; ++qsub) {
      const float* sb = (const float*)(smem + (kq * 4 + qs * 2 + qsub) * SLOT_SZ);
#pragma unroll
      for (int dt = 0; dt < 16; ++dt)
#pragma unroll
        for (int r = 0; r < 4; ++r)
          o[qsub][dt][r] += sb[(quad * 4 + r) * 260 + dt * 16 + l16];
    }
  }
  __syncthreads();
  if (kq == 1) {
#pragma unroll
    for (int qsub = 0; qsub < 2; ++qsub) {
      float* sb = (float*)(smem + (qs * 2 + qsub) * SLOT_SZ);
#pragma unroll
      for (int dt = 0; dt < 16; ++dt)
#pragma unroll
        for (int r = 0; r < 4; ++r)
          sb[(quad * 4 + r) * 260 + dt * 16 + l16] = o[qsub][dt][r];
    }
  }
  __syncthreads();
  if (kq == 0) {
#pragma unroll
    for (int qsub = 0; qsub < 2; ++qsub) {
      const float* sb = (const float*)(smem + (qs * 2 + qsub) * SLOT_SZ);
#pragma unroll
      for (int dt = 0; dt < 16; ++dt)
#pragma unroll
        for (int r = 0; r < 4; ++r) {
          const float v = o[qsub][dt][r] + sb[(quad * 4 + r) * 260 + dt * 16 + l16];
          out[(qrow0 + qsub * 16 + quad * 4 + r) * 256 + dt * 16 + l16] = v;
        }
    }
  }
}

extern "C" void kernel_launch(void* const* d_in, const int* in_sizes, int n_in,
                              void* d_out, int out_size, void* d_ws,
                              size_t ws_size, hipStream_t stream) {
  const float* x = (const float*)d_in[0];
  const float* Wq = (const float*)d_in[1];
  const float* bq = (const float*)d_in[2];
  const float* Wk = (const float*)d_in[3];
  const float* bk = (const float*)d_in[4];
  const float* Wv = (const float*)d_in[5];
  const float* bv = (const float*)d_in[6];
  float* out = (float*)d_out;
  char* ws = (char*)d_ws;

  prep_wt<<<768, 256, 0, stream>>>(Wq, Wk, Wv, (bf16*)(ws + WT_OFF));
  proj_qkv<<<1024, 256, 0, stream>>>(x, bq, bk, bv, ws);
  flash_attn<<<256, 512, 0, stream>>>(ws, out);
}

// Round 8
// 201.053 us; speedup vs baseline: 1.0586x; 1.0214x over previous
//
#include <hip/hip_runtime.h>

typedef __bf16 bf16;
typedef __bf16 bf16x4v __attribute__((ext_vector_type(4)));
typedef __bf16 bf16x8 __attribute__((ext_vector_type(8)));
typedef float f32x4 __attribute__((ext_vector_type(4)));
typedef short s16x4 __attribute__((ext_vector_type(4)));

#define MFMA_X32(A, B, C) __builtin_amdgcn_mfma_f32_16x16x32_bf16(A, B, C, 0, 0, 0)

#if __has_builtin(__builtin_amdgcn_mfma_f32_16x16x16_bf16)
static __device__ __forceinline__ f32x4 mfma_x16(bf16x4v a, bf16x4v b, f32x4 c) {
  return __builtin_amdgcn_mfma_f32_16x16x16_bf16(a, b, c, 0, 0, 0);
}
#else
static __device__ __forceinline__ f32x4 mfma_x16(bf16x4v a, bf16x4v b, f32x4 c) {
  return __builtin_amdgcn_mfma_f32_16x16x16bf16_1k(
      __builtin_bit_cast(s16x4, a), __builtin_bit_cast(s16x4, b), c, 0, 0, 0);
}
#endif

static __device__ __forceinline__ float fast_exp2(float x) {
  float r;
  asm volatile("v_exp_f32 %0, %1\n\ts_nop 0" : "=v"(r) : "v"(x));
  return r;
}

static __device__ __forceinline__ void gll16(const void* g, void* l) {
  __builtin_amdgcn_global_load_lds(
      (const __attribute__((address_space(1))) void*)g,
      (__attribute__((address_space(3))) void*)l, 16, 0, 0);
}

// ---- workspace byte offsets ----
#define WT_OFF 0              // Wt bf16 [3][256 n][256 k]          (384 KB)
#define Q_OFF 393216          // Q' bf16 [16384][256] (pre-scaled)   (8 MB)
#define K_OFF 8781824         // Kc bf16 chunk-permuted              (8 MB)
#define V_OFF 17170432        // Vc bf16 chunk-permuted              (8 MB)
// Kc: per (b, 16-key chunk) 8KB block; element (key s, dim n) at
//   (n>>5)*512 + ((n>>3)&3)*128 + (s&15)*8 + (n&7)
//   => flash K-frag ds_read_b128 addr = base + kt*1024 + lane*16 (LINEAR).
// Vc: per (b, 16-key chunk) 8KB block; element (key s, dim d=n) at
//   (n>>4)*256 + ((s&15)>>2)*64 + (n&15)*4 + (s&3)
//   => flash V-frag ds_read_b64 addr = base + dt*512 + lane*8 (LINEAR).
// (R3-verified layouts, unchanged.)

// ---------------------------------------------------------------------------
// Kernel 1 v2: W [k][n] fp32 -> Wt bf16 [p][n][k] via LDS-tiled 64x64
// transpose: both global accesses coalesced (v1's 512B-strided 2B stores were
// 64 transactions/wave). LDS stride 65 dwords => conflict-free.
// ---------------------------------------------------------------------------
__global__ __launch_bounds__(256) void prep_wt(const float* __restrict__ Wq,
                                               const float* __restrict__ Wk,
                                               const float* __restrict__ Wv,
                                               bf16* __restrict__ Wt) {
  __shared__ float lds[64][65];
  const int p = blockIdx.y;
  const int tile = blockIdx.x;  // 0..15
  const int k0 = (tile >> 2) * 64, n0 = (tile & 3) * 64;
  const float* W = (p == 0) ? Wq : ((p == 1) ? Wk : Wv);
  const int tid = threadIdx.x;
#pragma unroll
  for (int i = 0; i < 16; ++i) {  // read: consecutive tid -> consecutive n
    const int idx = i * 256 + tid;
    const int kk = idx >> 6, nn = idx & 63;
    lds[nn][kk] = W[(k0 + kk) * 256 + (n0 + nn)];
  }
  __syncthreads();
#pragma unroll
  for (int i = 0; i < 16; ++i) {  // write: consecutive tid -> consecutive k
    const int idx = i * 256 + tid;
    const int nn = idx >> 6, kk = idx & 63;
    Wt[p * 65536 + (n0 + nn) * 256 + (k0 + kk)] = (bf16)lds[nn][kk];
  }
}

// ---------------------------------------------------------------------------
// Kernel 2 v5: W-STATIONARY QKV projection. Grid (128 rowblocks, 6 groups);
// group = (p, 128-col half); block = 4 waves, wave owns 32 cols whose 16
// B-fragments live in REGISTERS (64 VGPR), loaded once — B is never re-read
// (v4 re-fetched B-frags from L2 for every 16 rows: 6x more VMEM instrs).
// Streams 4 chunks x 32 rows; zero LDS, zero barriers. 768 blocks = 3
// blk/CU = 3 waves/SIMD. Q pre-scaled by log2e/sqrt(D); K/V stored in the
// flash LDS permutations (R3-verified formulas, verbatim).
// ---------------------------------------------------------------------------
__global__ __launch_bounds__(256, 3) void proj_qkv(const float* __restrict__ x,
                                                   const float* __restrict__ bq,
                                                   const float* __restrict__ bk,
                                                   const float* __restrict__ bv,
                                                   char* __restrict__ ws0) {
  const bf16* Wt = (const bf16*)(ws0 + WT_OFF);
  bf16* Qo = (bf16*)(ws0 + Q_OFF);
  bf16* Ko = (bf16*)(ws0 + K_OFF);
  bf16* Vc = (bf16*)(ws0 + V_OFF);
  const int t = threadIdx.x;
  const int lane = t & 63, w = t >> 6, l16 = lane & 15, quad = lane >> 4;
  const int g = blockIdx.y;  // 0..5
  const int p = g >> 1;
  const int colbase = (g & 1) * 128 + w * 32;
  const int rowblk = blockIdx.x * 128;

  bf16x8 bfr[8][2];  // persistent B-frags: 32 cols x K=256 (one-time load)
#pragma unroll
  for (int kt = 0; kt < 8; ++kt)
#pragma unroll
    for (int nt = 0; nt < 2; ++nt)
      bfr[kt][nt] = *(const bf16x8*)&Wt[p * 65536 +
                                        (colbase + nt * 16 + l16) * 256 +
                                        kt * 32 + quad * 8];

  const float* bias = (p == 0) ? bq : ((p == 1) ? bk : bv);
  const float sc = (p == 0) ? 0.09016844005556021f : 1.0f;  // log2e/16
  const float bb[2] = {bias[colbase + l16], bias[colbase + 16 + l16]};

  for (int c = 0; c < 4; ++c) {
    const int rowc = rowblk + c * 32;
#pragma unroll
    for (int qsub = 0; qsub < 2; ++qsub) {
      const int arow = rowc + qsub * 16 + l16;
      bf16x8 a[8];
#pragma unroll
      for (int kt = 0; kt < 8; ++kt) {
        const float* xp = &x[arow * 256 + kt * 32 + quad * 8];
        const float4 v0 = *(const float4*)xp;
        const float4 v1 = *(const float4*)(xp + 4);
        bf16x8 h;
        h[0] = (bf16)v0.x; h[1] = (bf16)v0.y; h[2] = (bf16)v0.z; h[3] = (bf16)v0.w;
        h[4] = (bf16)v1.x; h[5] = (bf16)v1.y; h[6] = (bf16)v1.z; h[7] = (bf16)v1.w;
        a[kt] = h;
      }
      f32x4 acc[2] = {f32x4{0.f, 0.f, 0.f, 0.f}, f32x4{0.f, 0.f, 0.f, 0.f}};
#pragma unroll
      for (int kt = 0; kt < 8; ++kt)
#pragma unroll
        for (int nt = 0; nt < 2; ++nt)
          acc[nt] = MFMA_X32(a[kt], bfr[kt][nt], acc[nt]);

#pragma unroll
      for (int nt = 0; nt < 2; ++nt) {
        const int n = colbase + nt * 16 + l16;
#pragma unroll
        for (int r = 0; r < 4; ++r) {
          const int row = rowc + qsub * 16 + quad * 4 + r;  // C/D row=quad*4+r
          const bf16 hv = (bf16)((acc[nt][r] + bb[nt]) * sc);
          if (p == 0) {
            Qo[row * 256 + n] = hv;
          } else {
            const int b2 = row >> 11, s = row & 2047;
            if (p == 1)
              Ko[b2 * 524288 + (s >> 4) * 4096 + (n >> 5) * 512 +
                 ((n >> 3) & 3) * 128 + (s & 15) * 8 + (n & 7)] = hv;
            else
              Vc[b2 * 524288 + (s >> 4) * 4096 + (n >> 4) * 256 +
                 (((s & 15) >> 2)) * 64 + (n & 15) * 4 + (s & 3)] = hv;
          }
        }
      }
    }
  }
}

// ---------------------------------------------------------------------------
// Kernel 3: flash attention — byte-identical to R7's PASSING kernel.
// ---------------------------------------------------------------------------
#define BUF_SZ 65536   // half: 4 kq * (K 8KB + V 8KB), no pads
#define SLOT_SZ 16640  // merge slot: 16 rows * 260 floats

__global__ __launch_bounds__(512, 2) void flash_attn(const char* __restrict__ ws0,
                                                     float* __restrict__ out) {
  __shared__ __align__(1024) char smem[135168];  // 2*BUF_SZ + merge scratch
  const bf16* Qp = (const bf16*)(ws0 + Q_OFF);
  const int t = threadIdx.x;
  const int lane = t & 63, w = t >> 6;
  const int l16 = lane & 15, quad = lane >> 4;
  const int qs = w & 1, kq = w >> 1;
  const int b = blockIdx.x & 7;  // batch == XCD round-robin: K/V L2-resident
  const int qt = blockIdx.x >> 3;
  const int qrow0 = b * 2048 + qt * 64 + qs * 32;

  bf16x8 qf[2][8];
#pragma unroll
  for (int qsub = 0; qsub < 2; ++qsub)
#pragma unroll
    for (int kt = 0; kt < 8; ++kt)
      qf[qsub][kt] =
          *(const bf16x8*)&Qp[(qrow0 + qsub * 16 + l16) * 256 + kt * 32 + quad * 8];

  f32x4 o[2][16];
#pragma unroll
  for (int qsub = 0; qsub < 2; ++qsub)
#pragma unroll
    for (int dt = 0; dt < 16; ++dt) o[qsub][dt] = f32x4{0.f, 0.f, 0.f, 0.f};
  float m_[2] = {-1e30f, -1e30f}, l_[2] = {0.f, 0.f};

  // staging assignment: 8 GLL units (1 KB each) per wave per iter
  unsigned goff[8], loff[8];
#pragma unroll
  for (int i = 0; i < 8; ++i) {
    const int u = w * 8 + i;
    const int kq2 = (u & 31) >> 3, e = u & 7;
    goff[i] = (u < 32 ? (unsigned)K_OFF : (unsigned)V_OFF) + b * 1048576u +
              kq2 * 262144u + e * 1024u + lane * 16u;
    loff[i] = kq2 * 16384u + (u < 32 ? 0u : 8192u) + e * 1024u;
  }
#pragma unroll
  for (int i = 0; i < 8; ++i) gll16(ws0 + goff[i], smem + loff[i]);

  for (int it = 0; it < 32; ++it) {
    __syncthreads();  // chunk `it` resident; prev-iter reads of `nxt` done
    const unsigned cur = (unsigned)(it & 1) * BUF_SZ;
    if (it + 1 < 32) {
      const unsigned nxt = (unsigned)((it + 1) & 1) * BUF_SZ;
      const unsigned gadd = (unsigned)(it + 1) * 8192u;
#pragma unroll
      for (int i = 0; i < 8; ++i) gll16(ws0 + goff[i] + gadd, smem + nxt + loff[i]);
    }

    // ---- Sᵀ = K_chunk · Q'ᵀ (16 keys x 32 q); K reads LINEAR b128 ----
    const char* kb = smem + cur + kq * 16384 + lane * 16;
    f32x4 s0 = f32x4{0.f, 0.f, 0.f, 0.f}, s1 = s0;
#pragma unroll
    for (int kt = 0; kt < 8; ++kt) {
      const bf16x8 kf = *(const bf16x8*)(kb + kt * 1024);
      s0 = MFMA_X32(kf, qf[0][kt], s0);
      s1 = MFMA_X32(kf, qf[1][kt], s1);
    }

    // ---- online softmax (log2 domain; q = l16, key = quad*4+r) ----
    bf16x4v pa[2];
#pragma unroll
    for (int qsub = 0; qsub < 2; ++qsub) {
      const f32x4 s = qsub ? s1 : s0;
      float cm = fmaxf(fmaxf(s[0], s[1]), fmaxf(s[2], s[3]));
      cm = fmaxf(cm, __shfl_xor(cm, 16));
      cm = fmaxf(cm, __shfl_xor(cm, 32));
      const float mold = m_[qsub];
      const float mnew = fmaxf(mold, cm);
      bf16x4v pp;
      float ps = 0.f;
#pragma unroll
      for (int r = 0; r < 4; ++r) {
        const float e = fast_exp2(s[r] - mnew);
        const bf16 pb = (bf16)e;
        pp[r] = pb;
        ps += (float)pb;  // sum ROUNDED p for O/l consistency
      }
      ps += __shfl_xor(ps, 16);
      ps += __shfl_xor(ps, 32);
      if (__any(mnew > mold)) {
        const float al = fast_exp2(mold - mnew);
        m_[qsub] = mnew;
        l_[qsub] = l_[qsub] * al + ps;
        float ar[4];
#pragma unroll
        for (int r = 0; r < 4; ++r)
          ar[r] = __shfl(al, (quad << 4) + (quad << 2) + r);
#pragma unroll
        for (int dt = 0; dt < 16; ++dt)
#pragma unroll
          for (int r = 0; r < 4; ++r) o[qsub][dt][r] *= ar[r];
      } else {
        l_[qsub] += ps;
      }
      pa[qsub] = pp;  // Sᵀ C-frag == PV A-frag
    }

    // ---- O += P · V; V reads LINEAR b64 ----
    const char* vb = smem + cur + kq * 16384 + 8192 + lane * 8;
#pragma unroll
    for (int dt = 0; dt < 16; ++dt) {
      const bf16x4v vf = *(const bf16x4v*)(vb + dt * 512);
      o[0][dt] = mfma_x16(pa[0], vf, o[0][dt]);
      o[1][dt] = mfma_x16(pa[1], vf, o[1][dt]);
    }
  }

  // ---- merge 4 kq partials ----
  float* mlf = (float*)(smem + 133120);  // beyond both buffers: no race
  if (quad == 0) {
#pragma unroll
    for (int qsub = 0; qsub < 2; ++qsub) {
      const int base = ((kq * 2 + qs) * 2 + qsub) * 32;
      mlf[base + l16] = m_[qsub];
      mlf[base + 16 + l16] = l_[qsub];
    }
  }
  __syncthreads();
#pragma unroll
  for (int qsub = 0; qsub < 2; ++qsub) {
    float M = -1e30f, mk[4], lk[4];
#pragma unroll
    for (int k2 = 0; k2 < 4; ++k2) {
      const int base = ((k2 * 2 + qs) * 2 + qsub) * 32;
      mk[k2] = mlf[base + l16];
      lk[k2] = mlf[base + 16 + l16];
      M = fmaxf(M, mk[k2]);
    }
    float L = 0.f;
#pragma unroll
    for (int k2 = 0; k2 < 4; ++k2) L += lk[k2] * fast_exp2(mk[k2] - M);
    const float sg = fast_exp2(m_[qsub] - M) / L;
    float sr[4];
#pragma unroll
    for (int r = 0; r < 4; ++r) sr[r] = __shfl(sg, (quad << 4) + (quad << 2) + r);
#pragma unroll
    for (int dt = 0; dt < 16; ++dt)
#pragma unroll
      for (int r = 0; r < 4; ++r) o[qsub][dt][r] *= sr[r];
  }
  if (kq >= 2) {
#pragma unroll
    for (int qsub = 0; qsub < 2; ++qsub) {
      float* sb = (float*)(smem + ((kq - 2) * 4 + qs * 2 + qsub) * SLOT_SZ);
#pragma unroll
      for (int dt = 0; dt < 16; ++dt)
#pragma unroll
        for (int r = 0; r < 4; ++r)
          sb[(quad * 4 + r) * 260 + dt * 16 + l16] = o[qsub][dt][r];
    }
  }
  __syncthreads();
  if (kq < 2) {
#pragma unroll
    for (int qsub = 0; qsub < 2; ++qsub) {
      const float* sb = (const float*)(smem + (kq * 4 + qs * 2 + qsub) * SLOT_SZ);
#pragma unroll
      for (int dt = 0; dt < 16; ++dt)
#pragma unroll
        for (int r = 0; r < 4; ++r)
          o[qsub][dt][r] += sb[(quad * 4 + r) * 260 + dt * 16 + l16];
    }
  }
  __syncthreads();
  if (kq == 1) {
#pragma unroll
    for (int qsub = 0; qsub < 2; ++qsub) {
      float* sb = (float*)(smem + (qs * 2 + qsub) * SLOT_SZ);
#pragma unroll
      for (int dt = 0; dt < 16; ++dt)
#pragma unroll
        for (int r = 0; r < 4; ++r)
          sb[(quad * 4 + r) * 260 + dt * 16 + l16] = o[qsub][dt][r];
    }
  }
  __syncthreads();
  if (kq == 0) {
#pragma unroll
    for (int qsub = 0; qsub < 2; ++qsub) {
      const float* sb = (const float*)(smem + (qs * 2 + qsub) * SLOT_SZ);
#pragma unroll
      for (int dt = 0; dt < 16; ++dt)
#pragma unroll
        for (int r = 0; r < 4; ++r) {
          const float v = o[qsub][dt][r] + sb[(quad * 4 + r) * 260 + dt * 16 + l16];
          out[(qrow0 + qsub * 16 + quad * 4 + r) * 256 + dt * 16 + l16] = v;
        }
    }
  }
}

extern "C" void kernel_launch(void* const* d_in, const int* in_sizes, int n_in,
                              void* d_out, int out_size, void* d_ws,
                              size_t ws_size, hipStream_t stream) {
  const float* x = (const float*)d_in[0];
  const float* Wq = (const float*)d_in[1];
  const float* bq = (const float*)d_in[2];
  const float* Wk = (const float*)d_in[3];
  const float* bk = (const float*)d_in[4];
  const float* Wv = (const float*)d_in[5];
  const float* bv = (const float*)d_in[6];
  float* out = (float*)d_out;
  char* ws = (char*)d_ws;

  prep_wt<<<dim3(16, 3), 256, 0, stream>>>(Wq, Wk, Wv, (bf16*)(ws + WT_OFF));
  proj_qkv<<<dim3(128, 6), 256, 0, stream>>>(x, bq, bk, bv, ws);
  flash_attn<<<256, 512, 0, stream>>>(ws, out);
}